// Round 9
// baseline (252.128 us; speedup 1.0000x reference)
//
#include <hip/hip_runtime.h>
#include <math.h>

#define F_IN 128
#define H_DIM 64
#define C_OUT 40
#define NBK 391          // ceil(100000/256) coarse buckets, 256 nodes each
#define CHUNK 2048       // edges per binscatter block (782 blocks ~ 3/CU balance)
#define XPAD 136         // padded LDS half-stride (128 + 8) -> bank spread
#define PHB 128          // partial-histogram blocks (stateless CSR build, no memset)
#define BCAP 5120        // bucketsort LDS staging capacity (bucket ~4092 +- 64; 16 sigma)

typedef _Float16 h8 __attribute__((ext_vector_type(8)));   // 16B = 8 fp16 features
typedef _Float16 half2t __attribute__((ext_vector_type(2)));
typedef float nf4 __attribute__((ext_vector_type(4)));     // native float4 (nt-load-able)
typedef _Float16 f16x8 __attribute__((ext_vector_type(8)));
typedef float f32x4 __attribute__((ext_vector_type(4)));

union H8 {
    h8 v;
    half2t p[4];
};

__device__ __forceinline__ float dot8(const H8& a, const H8& b) {
    float d = __builtin_amdgcn_fdot2(a.p[0], b.p[0], 0.0f, false);
    d = __builtin_amdgcn_fdot2(a.p[1], b.p[1], d, false);
    d = __builtin_amdgcn_fdot2(a.p[2], b.p[2], d, false);
    d = __builtin_amdgcn_fdot2(a.p[3], b.p[3], d, false);
    return d;
}

// Butterfly add across the 8 sub-lanes (lane bits 0..2) using DPP only:
// xor1 = quad_perm(1,0,3,2)=0xB1, xor2 = quad_perm(2,3,0,1)=0x4E,
// cross-quad = row_half_mirror (0x141; valid since quads are uniform by then).
__device__ __forceinline__ float dpp_red8_add(float x) {
    int v = __builtin_bit_cast(int, x);
    x += __builtin_bit_cast(float, __builtin_amdgcn_update_dpp(0, v, 0xB1, 0xF, 0xF, true));
    v = __builtin_bit_cast(int, x);
    x += __builtin_bit_cast(float, __builtin_amdgcn_update_dpp(0, v, 0x4E, 0xF, 0xF, true));
    v = __builtin_bit_cast(int, x);
    x += __builtin_bit_cast(float, __builtin_amdgcn_update_dpp(0, v, 0x141, 0xF, 0xF, true));
    return x;
}

// ---------------- CSR build: two-level LDS counting sort ----------------
// pairs packed: (dst&255)<<24 | src   (src < 2^17)

// Stateless partial histogram (blocks 0..PHB-1) + fused W1->fp16 transpose
// (blocks PHB..PHB+31): independent front-of-launch work, one launch saved.
__global__ void __launch_bounds__(256) bphist_kernel(const int* __restrict__ dst,
                                                     int* __restrict__ part, int E,
                                                     const float* __restrict__ W1,
                                                     _Float16* __restrict__ w1t) {
    if (blockIdx.x >= PHB) {
        int t = (blockIdx.x - PHB) * 256 + threadIdx.x;
        if (t < F_IN * H_DIM) {
            int k = t >> 6, col = t & 63;
            w1t[col * F_IN + k] = (_Float16)W1[t];
        }
        return;
    }
    __shared__ int lh[512];
    int tid = threadIdx.x;
    lh[tid] = 0; lh[tid + 256] = 0;
    __syncthreads();
    int slice = (E + PHB - 1) / PHB;
    int lo = blockIdx.x * slice;
    int hi = min(E, lo + slice);
    for (int e = lo + tid; e < hi; e += 256) {
        int d = __builtin_nontemporal_load(&dst[e]);
        atomicAdd(&lh[d >> 8], 1);
    }
    __syncthreads();
    part[blockIdx.x * 512 + tid] = lh[tid];
    part[blockIdx.x * 512 + tid + 256] = lh[tid + 256];
}

__global__ void __launch_bounds__(512) bscan_kernel(const int* __restrict__ part,
                                                    int* __restrict__ bbase,
                                                    int* __restrict__ bcursor, int E) {
    __shared__ int sa[512], sb[512];
    int t = threadIdx.x;
    int v = 0;
#pragma unroll 4
    for (int b = 0; b < PHB; b++) v += part[b * 512 + t];
    sa[t] = v;
    __syncthreads();
    int* pa = sa; int* pb = sb;
#pragma unroll
    for (int off = 1; off < 512; off <<= 1) {
        pb[t] = pa[t] + ((t >= off) ? pa[t - off] : 0);
        __syncthreads();
        int* tmp = pa; pa = pb; pb = tmp;
    }
    if (t < NBK) {
        int excl = pa[t] - v;
        bbase[t] = excl;
        bcursor[t] = excl;
    }
    if (t == 0) bbase[NBK] = E;
}

// 512 threads, 2048-edge chunks: 782 blocks ~= 3/CU.
__global__ void __launch_bounds__(512) binscatter_kernel(const int* __restrict__ src,
                                                         const int* __restrict__ dst,
                                                         int* __restrict__ bcursor,
                                                         unsigned int* __restrict__ pairs, int E) {
    __shared__ unsigned int sp[CHUNK];
    __shared__ unsigned short sbof[CHUNK];
    __shared__ int hist[512];
    __shared__ int scanA[512], scanB[512];
    __shared__ int cur[512];
    __shared__ int gbase[512];
    int tid = threadIdx.x;
    int e0 = blockIdx.x * CHUNK;
    int cnt = min(CHUNK, E - e0);

    int dv[CHUNK / 512], sv[CHUNK / 512];
#pragma unroll
    for (int i = 0; i < CHUNK / 512; i++) {
        int idx = tid + i * 512;
        if (idx < cnt) {
            dv[i] = __builtin_nontemporal_load(&dst[e0 + idx]);
            sv[i] = __builtin_nontemporal_load(&src[e0 + idx]);
        }
    }
    hist[tid] = 0;
    __syncthreads();
#pragma unroll
    for (int i = 0; i < CHUNK / 512; i++) {
        int idx = tid + i * 512;
        if (idx < cnt) atomicAdd(&hist[dv[i] >> 8], 1);
    }
    __syncthreads();
    scanA[tid] = hist[tid];
    __syncthreads();
    int* pa = scanA; int* pb = scanB;
#pragma unroll
    for (int off = 1; off < 512; off <<= 1) {
        pb[tid] = pa[tid] + ((tid >= off) ? pa[tid - off] : 0);
        __syncthreads();
        int* tmp = pa; pa = pb; pb = tmp;
    }
    cur[tid] = pa[tid] - hist[tid];
    __syncthreads();
#pragma unroll
    for (int i = 0; i < CHUNK / 512; i++) {
        int idx = tid + i * 512;
        if (idx < cnt) {
            int b = dv[i] >> 8;
            int lp = atomicAdd(&cur[b], 1);
            sp[lp] = ((unsigned int)(dv[i] & 255) << 24) | (unsigned int)sv[i];
            sbof[lp] = (unsigned short)b;
        }
    }
    {
        int c0 = hist[tid];
        gbase[tid] = c0 ? atomicAdd(&bcursor[tid], c0) : 0;
    }
    __syncthreads();
    for (int i = tid; i < cnt; i += 512) {
        int b = sbof[i];
        int off_in_b = i - (pa[b] - hist[b]);
        pairs[gbase[b] + off_in_b] = sp[i];
    }
}

// 512 threads + LDS-staged pairs (bucket read from global once).
__global__ void __launch_bounds__(512) bucketsort_kernel(const unsigned int* __restrict__ pairs,
                                                         const int* __restrict__ bbase,
                                                         int* __restrict__ rowptr,
                                                         int* __restrict__ ssrc, int N, int E) {
    __shared__ unsigned int spairs[BCAP];
    __shared__ int hist[256], scanA[256], scanB[256], cur[256];
    int b = blockIdx.x;
    int tid = threadIdx.x;
    int e0 = bbase[b], e1 = bbase[b + 1];
    int cnt = e1 - e0;
    bool lds = cnt <= BCAP;

    if (tid < 256) hist[tid] = 0;
    if (lds) {
        for (int i = tid; i < cnt; i += 512) spairs[i] = pairs[e0 + i];
    }
    __syncthreads();
    for (int i = tid; i < cnt; i += 512) {
        unsigned int p = lds ? spairs[i] : pairs[e0 + i];
        atomicAdd(&hist[p >> 24], 1);
    }
    __syncthreads();
    if (tid < 256) scanA[tid] = hist[tid];
    __syncthreads();
    int* pa = scanA; int* pb = scanB;
#pragma unroll
    for (int off = 1; off < 256; off <<= 1) {
        if (tid < 256) pb[tid] = pa[tid] + ((tid >= off) ? pa[tid - off] : 0);
        __syncthreads();
        int* tmp = pa; pa = pb; pb = tmp;
    }
    if (tid < 256) {
        int excl = pa[tid] - hist[tid];
        int node = (b << 8) + tid;
        if (node < N) rowptr[node] = e0 + excl;
        cur[tid] = e0 + excl;
    }
    if (b == NBK - 1 && tid == 0) rowptr[N] = E;
    __syncthreads();
    for (int i = tid; i < cnt; i += 512) {
        unsigned int p = lds ? spairs[i] : pairs[e0 + i];
        int pos = atomicAdd(&cur[p >> 24], 1);
        ssrc[pos] = (int)(p & 0x00FFFFFFu);
    }
}

// ---- lin1 via MFMA: 64 rows/block; writes RAW relu fp16 rows (no norms;
// AGNN layers normalize on the fly from the gathered rows) ----
__global__ void __launch_bounds__(256) lin1_kernel(
        const float* __restrict__ x, const _Float16* __restrict__ w1t,
        const float* __restrict__ b1, _Float16* __restrict__ hnout, int n) {
    __shared__ _Float16 sx[64 * XPAD];
    __shared__ _Float16 sw[64 * XPAD];
    int tid = threadIdx.x;
    int r0 = blockIdx.x * 64;

    for (int ch = tid; ch < 64 * 32; ch += 256) {
        int row = ch >> 5, k4 = (ch & 31) << 2;
        float4 xv = make_float4(0.f, 0.f, 0.f, 0.f);
        if (r0 + row < n) xv = *(const float4*)(x + (size_t)(r0 + row) * F_IN + k4);
        _Float16* p = &sx[row * XPAD + k4];
        p[0] = (_Float16)xv.x; p[1] = (_Float16)xv.y;
        p[2] = (_Float16)xv.z; p[3] = (_Float16)xv.w;
    }
    for (int ch = tid; ch < 64 * 16; ch += 256) {
        int col = ch >> 4, k8 = (ch & 15) << 3;
        *(uint4*)&sw[col * XPAD + k8] = *(const uint4*)(w1t + col * F_IN + k8);
    }
    __syncthreads();

    int w = tid >> 6, lane = tid & 63;
    int q = lane >> 4, c = lane & 15;

    f16x8 afrag[4];
#pragma unroll
    for (int kk = 0; kk < 4; kk++)
        afrag[kk] = *(const f16x8*)&sx[(w * 16 + c) * XPAD + kk * 32 + q * 8];

    f32x4 acc[4] = {{0.f,0.f,0.f,0.f},{0.f,0.f,0.f,0.f},{0.f,0.f,0.f,0.f},{0.f,0.f,0.f,0.f}};
#pragma unroll
    for (int ct = 0; ct < 4; ct++) {
#pragma unroll
        for (int kk = 0; kk < 4; kk++) {
            f16x8 bfrag = *(const f16x8*)&sw[(ct * 16 + c) * XPAD + kk * 32 + q * 8];
            acc[ct] = __builtin_amdgcn_mfma_f32_16x16x32_f16(afrag[kk], bfrag, acc[ct], 0, 0, 0);
        }
    }

    __syncthreads();
#pragma unroll
    for (int ct = 0; ct < 4; ct++) {
        float bv = b1[ct * 16 + c];
#pragma unroll
        for (int r = 0; r < 4; r++) {
            float v = fmaxf(acc[ct][r] + bv, 0.0f);
            sx[(w * 16 + q * 4 + r) * XPAD + ct * 16 + c] = (_Float16)v;
        }
    }
    __syncthreads();
#pragma unroll
    for (int it = 0; it < 2; it++) {
        int row = w * 16 + it * 8 + (lane >> 3);
        int k8 = (lane & 7) * 8;
        if (r0 + row < n)
            *(uint4*)(hnout + (size_t)(r0 + row) * H_DIM + k8) =
                *(const uint4*)&sx[row * XPAD + k8];
    }
}

// ---- AGNN layer: 8 dst nodes per wave (8 lanes / node), 8-edge batches ----
// RAW h rows (no nrm side-array): per-src norm is computed on the fly from
// the gathered row (one extra dot8 + dpp reduce); logit = cos(x_d,x_s) =
// (x_d . x_s) * rsqrt|x_d|^2 * rsqrt|x_s|^2; aggregation uses the raw row
// directly (old w*nrm*hn == w*x). Removes 1.6M random 4B nrm gathers/layer
// (each a 64B L2 line fill -- the h stream thrashes L2 so these missed) and
// one dependent load per edge. Self weight = e (cos(x,x)=1); zero row -> 1.
// 2-deep pipeline pinned with sched_barrier(0) (R6/R7 lesson: the only
// fence the machine scheduler respects).
__global__ void __launch_bounds__(256, 3) agnn_kernel(
        const h8* __restrict__ h,
        const int* __restrict__ rowptr, const int* __restrict__ ssrc,
        h8* __restrict__ hout, int n, int E) {
    int wv = (blockIdx.x * blockDim.x + threadIdx.x) >> 6;   // global wave id
    int lane = threadIdx.x & 63;
    int g = lane >> 3;      // node slot 0..7
    int sub = lane & 7;     // feature chunk 0..7
    int wid = wv * 8 + g;   // dst node
    bool nvalid = wid < n;
    int nid = nvalid ? wid : (n - 1);

    int e0 = rowptr[nid];
    int e1 = rowptr[nid + 1];
    int steps = nvalid ? (e1 - e0) : 0;
    int eclamp = min(max(e1 - 1, e0), E - 1);   // node's own last edge (safe for deg 0)

    H8 hd; hd.v = h[(size_t)nid * 8 + sub];
    float nd2 = dpp_red8_add(dot8(hd, hd));          // |x_d|^2
    float rnd = rsqrtf(fmaxf(nd2, 1e-24f));          // 1/|x_d|

    // wave-uniform loop bound: max steps over the 8 groups (lane bits 3..5)
    int mx = steps;
    mx = max(mx, __shfl_xor(mx, 8, 64));
    mx = max(mx, __shfl_xor(mx, 16, 64));
    mx = max(mx, __shfl_xor(mx, 32, 64));

    // self loop: cos(x,x)=1 -> w=e (zero row: reference logit 0 -> w=1)
    float wself = (nd2 > 0.0f) ? 2.71828182845904523f : 1.0f;
    float sw = wself;
    half2t ap = {(_Float16)wself, (_Float16)wself};
    half2t acc2[4];
#pragma unroll
    for (int j = 0; j < 4; j++) acc2[j] = ap * hd.p[j];

    int sA[8], sB[8];
    H8 XA[8], XB[8];

    auto SLOAD = [&](int* s, int ofs) {
#pragma unroll
        for (int k = 0; k < 8; k++) s[k] = ssrc[min(e0 + ofs + k, eclamp)];
    };
    auto HLOAD = [&](const int* s, H8* X) {
#pragma unroll
        for (int k = 0; k < 8; k++) X[k].v = h[(size_t)s[k] * 8 + sub];
    };
    auto COMP = [&](const H8* X, int base) {
        float s2[8], d[8];
#pragma unroll
        for (int k = 0; k < 8; k++) s2[k] = dpp_red8_add(dot8(X[k], X[k]));
#pragma unroll
        for (int k = 0; k < 8; k++) d[k] = dpp_red8_add(dot8(X[k], hd));
#pragma unroll
        for (int k = 0; k < 8; k++) {
            float rs = rsqrtf(fmaxf(s2[k], 1e-24f));
            float wgt = (base + k < steps) ? __expf(d[k] * rnd * rs) : 0.0f;
            sw += wgt;
            half2t apk = {(_Float16)wgt, (_Float16)wgt};
#pragma unroll
            for (int j = 0; j < 4; j++) acc2[j] += apk * X[k].p[j];
        }
    };

    int nb = (mx + 7) >> 3;   // number of real 8-edge batches (wave-uniform)
    // prologue: batch 0 gathers + batch 1 indices
    SLOAD(sA, 0);
    __builtin_amdgcn_sched_barrier(0);
    HLOAD(sA, XA);
    SLOAD(sB, 8);
    __builtin_amdgcn_sched_barrier(0);

    int base = 0;
    for (int b = 0; b < nb; b += 2) {
        // issue batch b+1 gathers + batch b+2 indices; compute batch b
        HLOAD(sB, XB);
        SLOAD(sA, base + 16);
        __builtin_amdgcn_sched_barrier(0);
        COMP(XA, base);
        __builtin_amdgcn_sched_barrier(0);
        if (b + 1 >= nb) break;   // batch b+1 is pure padding: skip compute
        // issue batch b+2 gathers + batch b+3 indices; compute batch b+1
        HLOAD(sA, XA);
        SLOAD(sB, base + 24);
        __builtin_amdgcn_sched_barrier(0);
        COMP(XB, base + 8);
        __builtin_amdgcn_sched_barrier(0);
        base += 16;
    }

    float inv = 1.0f / sw;
    h8 oh;
#pragma unroll
    for (int j = 0; j < 4; j++) {
        oh[2 * j] = (_Float16)((float)acc2[j][0] * inv);
        oh[2 * j + 1] = (_Float16)((float)acc2[j][1] * inv);
    }
    if (nvalid) hout[(size_t)wid * 8 + sub] = oh;
}

// ---- lin2 + log_softmax: raw fp16 input, LDS-staged ----
__global__ void __launch_bounds__(256) lin2_kernel(
        const h8* __restrict__ h,
        const float* __restrict__ W2, const float* __restrict__ b2,
        float* __restrict__ out, int n) {
    __shared__ h8 sh[32 * 8];
    int tid = threadIdx.x;
    int r0 = blockIdx.x * 32;
    int rows = min(32, n - r0);

    {
        const uint4* hg = (const uint4*)(h + (size_t)r0 * 8);
        uint4* sh4 = (uint4*)sh;
        int tot = rows * 8;
        for (int i = tid; i < tot; i += 256) sh4[i] = hg[i];
    }
    __syncthreads();

    int wave = tid >> 6, lane = tid & 63;
    int rbase = wave * 8;

    float acc[8];
    if (lane < C_OUT) {
#pragma unroll
        for (int j = 0; j < 8; j++) acc[j] = 0.0f;
#pragma unroll 2
        for (int k = 0; k < H_DIM; k += 8) {
            float w[8];
#pragma unroll
            for (int i = 0; i < 8; i++) w[i] = W2[(k + i) * C_OUT + lane];
#pragma unroll
            for (int j = 0; j < 8; j++) {
                h8 hv = sh[(rbase + j) * 8 + (k >> 3)];
#pragma unroll
                for (int i = 0; i < 8; i++) acc[j] = fmaf((float)hv[i], w[i], acc[j]);
            }
        }
        float bl = b2[lane];
#pragma unroll
        for (int j = 0; j < 8; j++) acc[j] += bl;
    } else {
#pragma unroll
        for (int j = 0; j < 8; j++) acc[j] = -INFINITY;
    }

#pragma unroll
    for (int j = 0; j < 8; j++) {
        int r = rbase + j;
        if (r >= rows) break;
        float m = acc[j];
#pragma unroll
        for (int k = 1; k < 64; k <<= 1) m = fmaxf(m, __shfl_xor(m, k, 64));
        float e = (lane < C_OUT) ? __expf(acc[j] - m) : 0.0f;
        float s = e;
#pragma unroll
        for (int k = 1; k < 64; k <<= 1) s += __shfl_xor(s, k, 64);
        if (lane < C_OUT) out[(size_t)(r0 + r) * C_OUT + lane] = acc[j] - m - logf(s);
    }
}

// ---------------- launch ----------------

extern "C" void kernel_launch(void* const* d_in, const int* in_sizes, int n_in,
                              void* d_out, int out_size, void* d_ws, size_t ws_size,
                              hipStream_t stream) {
    const float* x = (const float*)d_in[0];
    const float* W1 = (const float*)d_in[1];
    const float* b1 = (const float*)d_in[2];
    const float* W2 = (const float*)d_in[3];
    const float* b2 = (const float*)d_in[4];
    const int* ei = (const int*)d_in[5];

    const int N = in_sizes[0] / F_IN;      // 100000
    const int E = in_sizes[5] / 2;         // 1600000
    const int* src = ei;
    const int* dst = ei + E;

    char* w = (char*)d_ws;
    auto carve = [&](size_t bytes) {
        char* p = w;
        w += (bytes + 255) & ~(size_t)255;
        return p;
    };
    _Float16* g1 = (_Float16*)carve((size_t)N * H_DIM * 2);
    _Float16* g2 = (_Float16*)carve((size_t)N * H_DIM * 2);   // aliased as pairs during CSR build
    int* rowptr = (int*)carve((size_t)(N + 1) * 4);
    int* bbase = (int*)carve(512 * 4);
    int* bcursor = (int*)carve(512 * 4);
    int* ssrc = (int*)carve((size_t)E * 4);
    _Float16* w1t = (_Float16*)carve((size_t)F_IN * H_DIM * 2);
    unsigned int* pairs = (unsigned int*)g2;  // 6.4 MB alias: dead before agnn layer 1 writes g2
    int* part = (int*)g1;                     // 256 KB alias: dead before lin1 writes g1

    // CSR build: two-level LDS counting sort, stateless (no memset/fill blit)
    bphist_kernel<<<PHB + 32, 256, 0, stream>>>(dst, part, E, W1, w1t);
    bscan_kernel<<<1, 512, 0, stream>>>(part, bbase, bcursor, E);
    binscatter_kernel<<<(E + CHUNK - 1) / CHUNK, 512, 0, stream>>>(src, dst, bcursor, pairs, E);
    bucketsort_kernel<<<NBK, 512, 0, stream>>>(pairs, bbase, rowptr, ssrc, N, E);

    // lin1 via MFMA: raw relu fp16 rows
    lin1_kernel<<<(N + 63) / 64, 256, 0, stream>>>(x, w1t, b1, g1, N);

    // 4 AGNN layers, ping-pong on raw fp16 h (8 nodes/wave -> 32 nodes/block)
    {
        int blocks = (N + 31) / 32;
        agnn_kernel<<<blocks, 256, 0, stream>>>((const h8*)g1, rowptr, ssrc, (h8*)g2, N, E);
        agnn_kernel<<<blocks, 256, 0, stream>>>((const h8*)g2, rowptr, ssrc, (h8*)g1, N, E);
        agnn_kernel<<<blocks, 256, 0, stream>>>((const h8*)g1, rowptr, ssrc, (h8*)g2, N, E);
        agnn_kernel<<<blocks, 256, 0, stream>>>((const h8*)g2, rowptr, ssrc, (h8*)g1, N, E);
    }

    // lin2 + log_softmax
    lin2_kernel<<<(N + 31) / 32, 256, 0, stream>>>((const h8*)g1, W2, b2, (float*)d_out, N);
}

// Round 10
// 246.679 us; speedup vs baseline: 1.0221x; 1.0221x over previous
//
#include <hip/hip_runtime.h>
#include <math.h>

#define F_IN 128
#define H_DIM 64
#define C_OUT 40
#define NBK 391          // ceil(100000/256) coarse buckets, 256 nodes each
#define CHUNK 4096       // edges per binscatter block
#define XPAD 136         // padded LDS half-stride (128 + 8) -> bank spread
#define PHB 128          // partial-histogram blocks (stateless CSR build, no memset)

typedef _Float16 h8 __attribute__((ext_vector_type(8)));   // 16B = 8 fp16 features
typedef _Float16 half2t __attribute__((ext_vector_type(2)));
typedef float nf4 __attribute__((ext_vector_type(4)));     // native float4 (nt-load-able)
typedef _Float16 f16x8 __attribute__((ext_vector_type(8)));
typedef float f32x4 __attribute__((ext_vector_type(4)));

union H8 {
    h8 v;
    half2t p[4];
};

__device__ __forceinline__ float dot8(const H8& a, const H8& b) {
    float d = __builtin_amdgcn_fdot2(a.p[0], b.p[0], 0.0f, false);
    d = __builtin_amdgcn_fdot2(a.p[1], b.p[1], d, false);
    d = __builtin_amdgcn_fdot2(a.p[2], b.p[2], d, false);
    d = __builtin_amdgcn_fdot2(a.p[3], b.p[3], d, false);
    return d;
}

// Butterfly add across the 8 sub-lanes (lane bits 0..2) using DPP only:
// xor1 = quad_perm(1,0,3,2)=0xB1, xor2 = quad_perm(2,3,0,1)=0x4E,
// cross-quad = row_half_mirror (0x141; valid since quads are uniform by then).
__device__ __forceinline__ float dpp_red8_add(float x) {
    int v = __builtin_bit_cast(int, x);
    x += __builtin_bit_cast(float, __builtin_amdgcn_update_dpp(0, v, 0xB1, 0xF, 0xF, true));
    v = __builtin_bit_cast(int, x);
    x += __builtin_bit_cast(float, __builtin_amdgcn_update_dpp(0, v, 0x4E, 0xF, 0xF, true));
    v = __builtin_bit_cast(int, x);
    x += __builtin_bit_cast(float, __builtin_amdgcn_update_dpp(0, v, 0x141, 0xF, 0xF, true));
    return x;
}

// ---------------- CSR build: two-level LDS counting sort ----------------
// pairs packed: (dst&255)<<24 | src   (src < 2^17)

// Stateless partial histogram: each block fully writes its own 512-bin slice
// (plain stores) -> no pre-zeroed global memory, no hipMemsetAsync.
__global__ void __launch_bounds__(256) bphist_kernel(const int* __restrict__ dst,
                                                     int* __restrict__ part, int E) {
    __shared__ int lh[512];
    int tid = threadIdx.x;
    lh[tid] = 0; lh[tid + 256] = 0;
    __syncthreads();
    int slice = (E + PHB - 1) / PHB;
    int lo = blockIdx.x * slice;
    int hi = min(E, lo + slice);
    for (int e = lo + tid; e < hi; e += 256) {
        int d = __builtin_nontemporal_load(&dst[e]);
        atomicAdd(&lh[d >> 8], 1);
    }
    __syncthreads();
    part[blockIdx.x * 512 + tid] = lh[tid];
    part[blockIdx.x * 512 + tid + 256] = lh[tid + 256];
}

__global__ void __launch_bounds__(512) bscan_kernel(const int* __restrict__ part,
                                                    int* __restrict__ bbase,
                                                    int* __restrict__ bcursor, int E) {
    __shared__ int sa[512], sb[512];
    int t = threadIdx.x;
    int v = 0;
#pragma unroll 4
    for (int b = 0; b < PHB; b++) v += part[b * 512 + t];
    sa[t] = v;
    __syncthreads();
    int* pa = sa; int* pb = sb;
#pragma unroll
    for (int off = 1; off < 512; off <<= 1) {
        pb[t] = pa[t] + ((t >= off) ? pa[t - off] : 0);
        __syncthreads();
        int* tmp = pa; pa = pb; pb = tmp;
    }
    if (t < NBK) {
        int excl = pa[t] - v;
        bbase[t] = excl;
        bcursor[t] = excl;
    }
    if (t == 0) bbase[NBK] = E;
}

__global__ void __launch_bounds__(256) binscatter_kernel(const int* __restrict__ src,
                                                         const int* __restrict__ dst,
                                                         int* __restrict__ bcursor,
                                                         unsigned int* __restrict__ pairs, int E) {
    __shared__ unsigned int sp[CHUNK];
    __shared__ unsigned short sbof[CHUNK];
    __shared__ int hist[512];
    __shared__ int scanA[512], scanB[512];
    __shared__ int cur[512];
    __shared__ int gbase[512];
    int tid = threadIdx.x;
    int e0 = blockIdx.x * CHUNK;
    int cnt = min(CHUNK, E - e0);

    int dv[CHUNK / 256], sv[CHUNK / 256];
#pragma unroll
    for (int i = 0; i < CHUNK / 256; i++) {
        int idx = tid + i * 256;
        if (idx < cnt) {
            dv[i] = __builtin_nontemporal_load(&dst[e0 + idx]);
            sv[i] = __builtin_nontemporal_load(&src[e0 + idx]);
        }
    }
    hist[tid] = 0; hist[tid + 256] = 0;
    __syncthreads();
#pragma unroll
    for (int i = 0; i < CHUNK / 256; i++) {
        int idx = tid + i * 256;
        if (idx < cnt) atomicAdd(&hist[dv[i] >> 8], 1);
    }
    __syncthreads();
    scanA[tid] = hist[tid]; scanA[tid + 256] = hist[tid + 256];
    __syncthreads();
    int* pa = scanA; int* pb = scanB;
#pragma unroll
    for (int off = 1; off < 512; off <<= 1) {
        pb[tid] = pa[tid] + ((tid >= off) ? pa[tid - off] : 0);
        int t1 = tid + 256;
        pb[t1] = pa[t1] + ((t1 >= off) ? pa[t1 - off] : 0);
        __syncthreads();
        int* tmp = pa; pa = pb; pb = tmp;
    }
    cur[tid] = pa[tid] - hist[tid];
    cur[tid + 256] = pa[tid + 256] - hist[tid + 256];
    __syncthreads();
#pragma unroll
    for (int i = 0; i < CHUNK / 256; i++) {
        int idx = tid + i * 256;
        if (idx < cnt) {
            int b = dv[i] >> 8;
            int lp = atomicAdd(&cur[b], 1);
            sp[lp] = ((unsigned int)(dv[i] & 255) << 24) | (unsigned int)sv[i];
            sbof[lp] = (unsigned short)b;
        }
    }
    {
        int c0 = hist[tid];
        gbase[tid] = c0 ? atomicAdd(&bcursor[tid], c0) : 0;
        int c1 = hist[tid + 256];
        gbase[tid + 256] = c1 ? atomicAdd(&bcursor[tid + 256], c1) : 0;
    }
    __syncthreads();
    for (int i = tid; i < cnt; i += 256) {
        int b = sbof[i];
        int off_in_b = i - (pa[b] - hist[b]);
        pairs[gbase[b] + off_in_b] = sp[i];
    }
}

__global__ void __launch_bounds__(256) bucketsort_kernel(const unsigned int* __restrict__ pairs,
                                                         const int* __restrict__ bbase,
                                                         int* __restrict__ rowptr,
                                                         int* __restrict__ ssrc, int N, int E) {
    __shared__ int hist[256], scanA[256], scanB[256], cur[256];
    int b = blockIdx.x;
    int tid = threadIdx.x;
    int e0 = bbase[b], e1 = bbase[b + 1];
    hist[tid] = 0;
    __syncthreads();
    for (int e = e0 + tid; e < e1; e += 256) {
        unsigned int p = pairs[e];
        atomicAdd(&hist[p >> 24], 1);
    }
    __syncthreads();
    scanA[tid] = hist[tid];
    __syncthreads();
    int* pa = scanA; int* pb = scanB;
#pragma unroll
    for (int off = 1; off < 256; off <<= 1) {
        pb[tid] = pa[tid] + ((tid >= off) ? pa[tid - off] : 0);
        __syncthreads();
        int* tmp = pa; pa = pb; pb = tmp;
    }
    int excl = pa[tid] - hist[tid];
    int node = (b << 8) + tid;
    if (node < N) rowptr[node] = e0 + excl;
    if (b == NBK - 1 && tid == 0) rowptr[N] = E;
    cur[tid] = e0 + excl;
    __syncthreads();
    for (int e = e0 + tid; e < e1; e += 256) {
        unsigned int p = pairs[e];
        int pos = atomicAdd(&cur[p >> 24], 1);
        ssrc[pos] = (int)(p & 0x00FFFFFFu);
    }
}

// ---- W1 -> fp16 transposed [col][k] (once per launch; 16 KB, L2-resident) ----
__global__ void __launch_bounds__(256) cvtw_kernel(const float* __restrict__ W1,
                                                   _Float16* __restrict__ w1t) {
    int t = blockIdx.x * 256 + threadIdx.x;
    if (t < F_IN * H_DIM) {
        int k = t >> 6, col = t & 63;
        w1t[col * F_IN + k] = (_Float16)W1[t];
    }
}

// ---- lin1 via MFMA: 64 rows/block; writes normalized fp16 + norms ----
__global__ void __launch_bounds__(256) lin1_kernel(
        const float* __restrict__ x, const _Float16* __restrict__ w1t,
        const float* __restrict__ b1, _Float16* __restrict__ hnout,
        float* __restrict__ nrmout, int n) {
    __shared__ _Float16 sx[64 * XPAD];
    __shared__ _Float16 sw[64 * XPAD];
    int tid = threadIdx.x;
    int r0 = blockIdx.x * 64;

    for (int ch = tid; ch < 64 * 32; ch += 256) {
        int row = ch >> 5, k4 = (ch & 31) << 2;
        float4 xv = make_float4(0.f, 0.f, 0.f, 0.f);
        if (r0 + row < n) xv = *(const float4*)(x + (size_t)(r0 + row) * F_IN + k4);
        _Float16* p = &sx[row * XPAD + k4];
        p[0] = (_Float16)xv.x; p[1] = (_Float16)xv.y;
        p[2] = (_Float16)xv.z; p[3] = (_Float16)xv.w;
    }
    for (int ch = tid; ch < 64 * 16; ch += 256) {
        int col = ch >> 4, k8 = (ch & 15) << 3;
        *(uint4*)&sw[col * XPAD + k8] = *(const uint4*)(w1t + col * F_IN + k8);
    }
    __syncthreads();

    int w = tid >> 6, lane = tid & 63;
    int q = lane >> 4, c = lane & 15;

    f16x8 afrag[4];
#pragma unroll
    for (int kk = 0; kk < 4; kk++)
        afrag[kk] = *(const f16x8*)&sx[(w * 16 + c) * XPAD + kk * 32 + q * 8];

    f32x4 acc[4] = {{0.f,0.f,0.f,0.f},{0.f,0.f,0.f,0.f},{0.f,0.f,0.f,0.f},{0.f,0.f,0.f,0.f}};
#pragma unroll
    for (int ct = 0; ct < 4; ct++) {
#pragma unroll
        for (int kk = 0; kk < 4; kk++) {
            f16x8 bfrag = *(const f16x8*)&sw[(ct * 16 + c) * XPAD + kk * 32 + q * 8];
            acc[ct] = __builtin_amdgcn_mfma_f32_16x16x32_f16(afrag[kk], bfrag, acc[ct], 0, 0, 0);
        }
    }

    float ss[4] = {0.f, 0.f, 0.f, 0.f};
#pragma unroll
    for (int ct = 0; ct < 4; ct++) {
        float bv = b1[ct * 16 + c];
#pragma unroll
        for (int r = 0; r < 4; r++) {
            float v = fmaxf(acc[ct][r] + bv, 0.0f);
            acc[ct][r] = v;
            ss[r] = fmaf(v, v, ss[r]);
        }
    }
#pragma unroll
    for (int k = 1; k < 16; k <<= 1) {
#pragma unroll
        for (int r = 0; r < 4; r++) ss[r] += __shfl_xor(ss[r], k, 64);
    }
    float nn[4], inv[4];
#pragma unroll
    for (int r = 0; r < 4; r++) {
        nn[r] = fmaxf(sqrtf(ss[r]), 1e-12f);
        inv[r] = 1.0f / nn[r];
    }
#pragma unroll
    for (int ct = 0; ct < 4; ct++)
#pragma unroll
        for (int r = 0; r < 4; r++)
            sx[(w * 16 + q * 4 + r) * XPAD + ct * 16 + c] = (_Float16)(acc[ct][r] * inv[r]);

    if (c == 0) {
#pragma unroll
        for (int r = 0; r < 4; r++) {
            int row = r0 + w * 16 + q * 4 + r;
            if (row < n) nrmout[row] = nn[r];
        }
    }
#pragma unroll
    for (int it = 0; it < 2; it++) {
        int row = w * 16 + it * 8 + (lane >> 3);
        int k8 = (lane & 7) * 8;
        if (r0 + row < n)
            *(uint4*)(hnout + (size_t)(r0 + row) * H_DIM + k8) =
                *(const uint4*)&sx[row * XPAD + k8];
    }
}

// ---- AGNN layer: 8 dst nodes per wave (8 lanes / node), 8-edge batches ----
// 2-deep software pipeline, regions pinned with sched_barrier(0) (the only
// mechanism that survives the machine scheduler -- R3/R4/R5 evidence):
//   region: { HLOAD(batch t+1) ; SLOAD(indices t+2) }  fence
//   region: { COMP(batch t) }                          fence
// Batch t's gathers are OLDER than t+1's, so the compiler's auto-waitcnt
// before COMP(t) is a counted vmcnt that leaves t+1's 24 loads in flight
// under the compute. Padding slots clamp to the node's own last edge
// (same cache line, no extra traffic).
// FINAL STATE (best measured 246.4 us): agnn FETCH ~90 MB/layer is
// COMPULSORY (8 XCDs x ~86% of the 12.8 MB h array = 88 MB) -- random
// gathers across private L2s; R7 depth / R8 CSR / R9 nrm-elim all neutral.
__global__ void __launch_bounds__(256, 3) agnn_kernel(
        const h8* __restrict__ h, const float* __restrict__ nrm,
        const int* __restrict__ rowptr, const int* __restrict__ ssrc,
        h8* __restrict__ hout, float* __restrict__ nrmout, int n, int E) {
    int wv = (blockIdx.x * blockDim.x + threadIdx.x) >> 6;   // global wave id
    int lane = threadIdx.x & 63;
    int g = lane >> 3;      // node slot 0..7
    int sub = lane & 7;     // feature chunk 0..7
    int wid = wv * 8 + g;   // dst node
    bool nvalid = wid < n;
    int nid = nvalid ? wid : (n - 1);

    int e0 = rowptr[nid];
    int e1 = rowptr[nid + 1];
    int steps = nvalid ? (e1 - e0) : 0;
    int eclamp = min(max(e1 - 1, e0), E - 1);   // node's own last edge (safe for deg 0)

    H8 hd; hd.v = h[(size_t)nid * 8 + sub];
    float ni = nrm[nid];

    // wave-uniform loop bound: max steps over the 8 groups (lane bits 3..5)
    int mx = steps;
    mx = max(mx, __shfl_xor(mx, 8, 64));
    mx = max(mx, __shfl_xor(mx, 16, 64));
    mx = max(mx, __shfl_xor(mx, 32, 64));

    // self loop
    float dself = dpp_red8_add(dot8(hd, hd));
    float wself = __expf(dself);
    float sw = wself;
    float aself = wself * ni;
    half2t ap = {(_Float16)aself, (_Float16)aself};
    half2t acc2[4];
#pragma unroll
    for (int j = 0; j < 4; j++) acc2[j] = ap * hd.p[j];

    int sA[8], sB[8];
    H8 XA[8], XB[8];
    float nA[8], nB[8];

    auto SLOAD = [&](int* s, int ofs) {
#pragma unroll
        for (int k = 0; k < 8; k++) s[k] = ssrc[min(e0 + ofs + k, eclamp)];
    };
    auto HLOAD = [&](const int* s, H8* X, float* xn) {
#pragma unroll
        for (int k = 0; k < 8; k++) {
            X[k].v = h[(size_t)s[k] * 8 + sub];
            xn[k] = nrm[s[k]];
        }
    };
    auto COMP = [&](const H8* X, const float* xn, int base) {
        float d[8];
#pragma unroll
        for (int k = 0; k < 8; k++) d[k] = dpp_red8_add(dot8(X[k], hd));
#pragma unroll
        for (int k = 0; k < 8; k++) {
            float wgt = (base + k < steps) ? __expf(d[k]) : 0.0f;
            sw += wgt;
            float a = wgt * xn[k];
            half2t apk = {(_Float16)a, (_Float16)a};
#pragma unroll
            for (int j = 0; j < 4; j++) acc2[j] += apk * X[k].p[j];
        }
    };

    int nb = (mx + 7) >> 3;   // number of real 8-edge batches (wave-uniform)
    // prologue: batch 0 gathers + batch 1 indices
    SLOAD(sA, 0);
    __builtin_amdgcn_sched_barrier(0);
    HLOAD(sA, XA, nA);
    SLOAD(sB, 8);
    __builtin_amdgcn_sched_barrier(0);

    int base = 0;
    for (int b = 0; b < nb; b += 2) {
        // issue batch b+1 gathers + batch b+2 indices; compute batch b
        HLOAD(sB, XB, nB);
        SLOAD(sA, base + 16);
        __builtin_amdgcn_sched_barrier(0);
        COMP(XA, nA, base);
        __builtin_amdgcn_sched_barrier(0);
        if (b + 1 >= nb) break;   // batch b+1 is pure padding: skip compute
        // issue batch b+2 gathers + batch b+3 indices; compute batch b+1
        HLOAD(sA, XA, nA);
        SLOAD(sB, base + 24);
        __builtin_amdgcn_sched_barrier(0);
        COMP(XB, nB, base + 8);
        __builtin_amdgcn_sched_barrier(0);
        base += 16;
    }

    float inv = 1.0f / sw;
    float o[8];
#pragma unroll
    for (int j = 0; j < 4; j++) {
        o[2 * j] = (float)acc2[j][0] * inv;
        o[2 * j + 1] = (float)acc2[j][1] * inv;
    }
    float ss = 0.0f;
#pragma unroll
    for (int i = 0; i < 8; i++) ss = fmaf(o[i], o[i], ss);
    ss = dpp_red8_add(ss);
    float nn = fmaxf(sqrtf(ss), 1e-12f);
    float r = 1.0f / nn;
    h8 oh;
#pragma unroll
    for (int i = 0; i < 8; i++) oh[i] = (_Float16)(o[i] * r);
    if (nvalid) {
        hout[(size_t)wid * 8 + sub] = oh;
        if (sub == 0) nrmout[wid] = nn;
    }
}

// ---- lin2 + log_softmax: normalized fp16 input + per-row norm, LDS-staged ----
__global__ void __launch_bounds__(256) lin2_kernel(
        const h8* __restrict__ h, const float* __restrict__ nrm,
        const float* __restrict__ W2, const float* __restrict__ b2,
        float* __restrict__ out, int n) {
    __shared__ h8 sh[32 * 8];
    __shared__ float snrm[32];
    int tid = threadIdx.x;
    int r0 = blockIdx.x * 32;
    int rows = min(32, n - r0);

    {
        const uint4* hg = (const uint4*)(h + (size_t)r0 * 8);
        uint4* sh4 = (uint4*)sh;
        int tot = rows * 8;
        for (int i = tid; i < tot; i += 256) sh4[i] = hg[i];
        if (tid < rows) snrm[tid] = nrm[r0 + tid];
    }
    __syncthreads();

    int wave = tid >> 6, lane = tid & 63;
    int rbase = wave * 8;

    float acc[8];
    if (lane < C_OUT) {
#pragma unroll
        for (int j = 0; j < 8; j++) acc[j] = 0.0f;
#pragma unroll 2
        for (int k = 0; k < H_DIM; k += 8) {
            float w[8];
#pragma unroll
            for (int i = 0; i < 8; i++) w[i] = W2[(k + i) * C_OUT + lane];
#pragma unroll
            for (int j = 0; j < 8; j++) {
                h8 hv = sh[(rbase + j) * 8 + (k >> 3)];
#pragma unroll
                for (int i = 0; i < 8; i++) acc[j] = fmaf((float)hv[i], w[i], acc[j]);
            }
        }
        float bl = b2[lane];
#pragma unroll
        for (int j = 0; j < 8; j++) acc[j] = fmaf(snrm[rbase + j], acc[j], bl);
    } else {
#pragma unroll
        for (int j = 0; j < 8; j++) acc[j] = -INFINITY;
    }

#pragma unroll
    for (int j = 0; j < 8; j++) {
        int r = rbase + j;
        if (r >= rows) break;
        float m = acc[j];
#pragma unroll
        for (int k = 1; k < 64; k <<= 1) m = fmaxf(m, __shfl_xor(m, k, 64));
        float e = (lane < C_OUT) ? __expf(acc[j] - m) : 0.0f;
        float s = e;
#pragma unroll
        for (int k = 1; k < 64; k <<= 1) s += __shfl_xor(s, k, 64);
        if (lane < C_OUT) out[(size_t)(r0 + r) * C_OUT + lane] = acc[j] - m - logf(s);
    }
}

// ---------------- launch ----------------

extern "C" void kernel_launch(void* const* d_in, const int* in_sizes, int n_in,
                              void* d_out, int out_size, void* d_ws, size_t ws_size,
                              hipStream_t stream) {
    const float* x = (const float*)d_in[0];
    const float* W1 = (const float*)d_in[1];
    const float* b1 = (const float*)d_in[2];
    const float* W2 = (const float*)d_in[3];
    const float* b2 = (const float*)d_in[4];
    const int* ei = (const int*)d_in[5];

    const int N = in_sizes[0] / F_IN;      // 100000
    const int E = in_sizes[5] / 2;         // 1600000
    const int* src = ei;
    const int* dst = ei + E;

    char* w = (char*)d_ws;
    auto carve = [&](size_t bytes) {
        char* p = w;
        w += (bytes + 255) & ~(size_t)255;
        return p;
    };
    _Float16* g1 = (_Float16*)carve((size_t)N * H_DIM * 2);
    _Float16* g2 = (_Float16*)carve((size_t)N * H_DIM * 2);   // aliased as pairs during CSR build
    float* rn1 = (float*)carve((size_t)N * 4);
    float* rn2 = (float*)carve((size_t)N * 4);
    int* rowptr = (int*)carve((size_t)(N + 1) * 4);
    int* bbase = (int*)carve(512 * 4);
    int* bcursor = (int*)carve(512 * 4);
    int* ssrc = (int*)carve((size_t)E * 4);
    _Float16* w1t = (_Float16*)carve((size_t)F_IN * H_DIM * 2);
    unsigned int* pairs = (unsigned int*)g2;  // 6.4 MB alias: dead before agnn layer 1 writes g2
    int* part = (int*)g1;                     // 256 KB alias: dead before lin1 writes g1

    // CSR build: two-level LDS counting sort, stateless (no memset/fill blit)
    bphist_kernel<<<PHB, 256, 0, stream>>>(dst, part, E);
    bscan_kernel<<<1, 512, 0, stream>>>(part, bbase, bcursor, E);
    binscatter_kernel<<<(E + CHUNK - 1) / CHUNK, 256, 0, stream>>>(src, dst, bcursor, pairs, E);
    bucketsort_kernel<<<NBK, 256, 0, stream>>>(pairs, bbase, rowptr, ssrc, N, E);

    // lin1 via MFMA: normalized fp16 rows + norms
    cvtw_kernel<<<(F_IN * H_DIM + 255) / 256, 256, 0, stream>>>(W1, w1t);
    lin1_kernel<<<(N + 63) / 64, 256, 0, stream>>>(x, w1t, b1, g1, rn1, N);

    // 4 AGNN layers, ping-pong on normalized fp16 h (8 nodes/wave -> 32 nodes/block)
    {
        int blocks = (N + 31) / 32;
        agnn_kernel<<<blocks, 256, 0, stream>>>((const h8*)g1, rn1, rowptr, ssrc, (h8*)g2, rn2, N, E);
        agnn_kernel<<<blocks, 256, 0, stream>>>((const h8*)g2, rn2, rowptr, ssrc, (h8*)g1, rn1, N, E);
        agnn_kernel<<<blocks, 256, 0, stream>>>((const h8*)g1, rn1, rowptr, ssrc, (h8*)g2, rn2, N, E);
        agnn_kernel<<<blocks, 256, 0, stream>>>((const h8*)g2, rn2, rowptr, ssrc, (h8*)g1, rn1, N, E);
    }

    // lin2 + log_softmax
    lin2_kernel<<<(N + 31) / 32, 256, 0, stream>>>((const h8*)g1, rn1, W2, b2, (float*)d_out, N);
}